// Round 9
// baseline (161.725 us; speedup 1.0000x reference)
//
#include <hip/hip_runtime.h>

// IM2HT Hough voting:
//   out[b,c,ht] = sum_{n: ht_idx[n]==ht} input_im[b,c,im_idx[n]] * weight[n]
// B*C = 128, HW = 16384, NHT = 184*180 = 33120, N = 1.5M votes.
//
// Pipeline (4 kernels):
//   1. k_init   : transpose in[BC][HW] -> xTh[HW][128] bf16 (4 MB = one XCD L2)
//                 + zero bucket cursors/overflow counter (fused by block idx)
//   2. k_bucket : multi-split votes into 552 coarse ht-ranges (60 bins each);
//                 1024 thr x 4 votes; per-block private chunks -> merged writes
//   3. k_resort : per-range LDS-staged counting sort -> fine-bin-contiguous
//                 records, bins padded to multiple of 4 (weight-0 dummies)
//   4. k_accum6 : 512-thr block owns 32 consecutive bins (NHT = 1035*32); each
//                 wave: 4 bins via quarter-wave bf16x8 gathers (1 gather instr
//                 per 4 votes, L2-resident) + shfl reduce -> LDS acc[32][129];
//                 block writes out[ch][ht0+j] directly (transpose fused);
//                 overflow records folded in (empty in practice)

#define HW   16384
#define BC   128
#define NHT  33120
#define RB   60            // ht bins per coarse range
#define NB   552           // NHT / RB
#define CAPB 3712          // slots per range incl. padding (mean 2717)
#define CAPR 3528          // raw record clamp (184 pad slots), +15 sigma
#define VPB  4096          // votes per k_bucket block
#define OFL_CAP 8192

typedef int iv4 __attribute__((ext_vector_type(4)));

__device__ __forceinline__ unsigned short f2bf(float f) {
  unsigned int u = __float_as_uint(f);
  u = (u + 0x7fff + ((u >> 16) & 1)) >> 16;   // round-to-nearest-even
  return (unsigned short)u;
}

// blocks 0..2047: transpose in[BC][HW] f32 -> xTh[HW][BC] bf16; block 2048: zero
__global__ void k_init(const float* __restrict__ in, unsigned short* __restrict__ xTh,
                       int* __restrict__ gcur, int* __restrict__ ofl_cnt) {
  if (blockIdx.x == 2048) {
    int tid = threadIdx.y * 32 + threadIdx.x;
    for (int i = tid; i < NB; i += 256) gcur[i] = 0;
    if (tid == 0) *ofl_cnt = 0;
    return;
  }
  __shared__ float tile[32][33];
  int hw0 = (blockIdx.x & 511) * 32, bc0 = (blockIdx.x >> 9) * 32;
  int tx = threadIdx.x, ty = threadIdx.y;
#pragma unroll
  for (int k = 0; k < 32; k += 8)
    tile[ty + k][tx] = in[(size_t)(bc0 + ty + k) * HW + hw0 + tx];  // coalesced on hw
  __syncthreads();
#pragma unroll
  for (int k = 0; k < 32; k += 8)
    xTh[(size_t)(hw0 + ty + k) * BC + bc0 + tx] = f2bf(tile[tx][ty + k]);
}

// 1024 threads, 4 votes each (VPB = 4096 -> private-chunk write combining)
__global__ __launch_bounds__(1024) void k_bucket(
    const int* __restrict__ im, const int* __restrict__ ht,
    const float* __restrict__ wt, int n,
    int* __restrict__ gcur, int2* __restrict__ bkt,
    int* __restrict__ ofl_cnt, int2* __restrict__ ofl) {
  __shared__ int cnt[NB];
  __shared__ int base[NB];
  int tid = threadIdx.x;
  int i0 = blockIdx.x * VPB;
  for (int b = tid; b < NB; b += 1024) cnt[b] = 0;
  __syncthreads();
  int hv[4];
#pragma unroll
  for (int k = 0; k < 4; ++k) {
    int i = i0 + k * 1024 + tid;
    hv[k] = (i < n) ? ht[i] : -1;
    if (i < n) atomicAdd(&cnt[hv[k] / RB], 1);
  }
  __syncthreads();
  for (int b = tid; b < NB; b += 1024) {
    int c = cnt[b];
    base[b] = c ? atomicAdd(&gcur[b], c) : 0;  // reserve private chunk
    cnt[b] = 0;                                 // reuse as local cursor
  }
  __syncthreads();
#pragma unroll
  for (int k = 0; k < 4; ++k) {
    int i = i0 + k * 1024 + tid;
    if (i < n) {
      int h = hv[k];
      int b = h / RB;
      int hl = h - b * RB;
      int pos = base[b] + atomicAdd(&cnt[b], 1);
      if (pos < CAPR) {
        bkt[(size_t)b * CAPB + pos] =
            make_int2((im[i] & 0x3FFF) | (hl << 14), __float_as_int(wt[i]));
      } else {
        int o = atomicAdd(ofl_cnt, 1);
        if (o < OFL_CAP)
          ofl[o] = make_int2((im[i] & 0x3FFF) | (h << 14), __float_as_int(wt[i]));
      }
    }
  }
}

// per-range LDS-staged counting sort; bins padded to multiple of 4
__global__ __launch_bounds__(512) void k_resort(
    const int2* __restrict__ bkt, const int* __restrict__ gcur,
    int2* __restrict__ fsorted, int* __restrict__ foffs, int* __restrict__ fcnt) {
  __shared__ int2 buf[CAPB];     // 29.7 KB staged records
  __shared__ int hist[RB];
  __shared__ int off[RB];
  int r = blockIdx.x, tid = threadIdx.x;
  int n = gcur[r];
  if (n > CAPR) n = CAPR;
  const int2* s = bkt + (size_t)r * CAPB;
  for (int i = tid; i < n; i += 512) buf[i] = s[i];   // single global read
  if (tid < RB) hist[tid] = 0;
  __syncthreads();
  for (int i = tid; i < n; i += 512)
    atomicAdd(&hist[buf[i].x >> 14], 1);
  __syncthreads();
  if (tid == 0) {
    int run = 0;
    for (int b = 0; b < RB; ++b) { off[b] = run; run += (hist[b] + 3) & ~3; }
  }
  __syncthreads();
  if (tid < RB) {
    int padded = (hist[tid] + 3) & ~3;
    foffs[r * RB + tid] = r * CAPB + off[tid];
    fcnt[r * RB + tid] = padded;
    for (int d = hist[tid]; d < padded; ++d)        // weight-0 dummies
      fsorted[(size_t)r * CAPB + off[tid] + d] = make_int2(0, 0);
    hist[tid] = 0;  // reuse as cursor
  }
  __syncthreads();
  for (int i = tid; i < n; i += 512) {
    int2 v = buf[i];
    int hl = v.x >> 14;
    int pos = off[hl] + atomicAdd(&hist[hl], 1);
    fsorted[(size_t)r * CAPB + pos] = make_int2(v.x & 0x3FFF, v.y);
  }
}

// select vote q's (im, w) from 4 packed records
__device__ __forceinline__ void pick4(iv4 a, iv4 b, int q, int& im, float& w) {
  int imx = (q & 2) ? b.x : a.x;
  int imz = (q & 2) ? b.z : a.z;
  im = (q & 1) ? imz : imx;
  int wx = (q & 2) ? b.y : a.y;
  int wz = (q & 2) ? b.w : a.w;
  w = __int_as_float((q & 1) ? wz : wx);
}

// 512-thr block = 32 consecutive bins; wave w handles bins w*4..w*4+3;
// lane = (vote quarter q, channel octet cg); transposed write-out fused
__global__ __launch_bounds__(512) void k_accum6(
    const int2* __restrict__ fsorted, const int* __restrict__ foffs,
    const int* __restrict__ fcnt, const unsigned short* __restrict__ xTh,
    float* __restrict__ out, const int* __restrict__ ofl_cnt,
    const int2* __restrict__ ofl) {
  __shared__ float lacc[32 * 129];   // [bin][ch], stride 129 -> conflict-free reads
  int tid = threadIdx.x;
  int ht0 = blockIdx.x * 32;
  int w = __builtin_amdgcn_readfirstlane(tid >> 6);   // wave id 0..7
  int lane = tid & 63;
  int q = lane >> 4;       // vote quarter 0..3
  int cg = lane & 15;      // channel octet: channels 8*cg .. 8*cg+7
  const unsigned short* xb = xTh + (cg << 3);

#pragma unroll
  for (int bi = 0; bi < 4; ++bi) {
    int bin = ht0 + w * 4 + bi;
    int start = foffs[bin], n = fcnt[bin];  // n % 4 == 0
    const int* s = (const int*)(fsorted + start);
    float acc[8] = {0, 0, 0, 0, 0, 0, 0, 0};

#define GATHER_FMA(IM, W)                                                     \
  {                                                                           \
    iv4 xd = *(const iv4*)(xb + ((size_t)(IM) << 7));                         \
    _Pragma("unroll") for (int c = 0; c < 4; ++c) {                           \
      float lo = __uint_as_float(((unsigned int)xd[c]) << 16);                \
      float hi = __uint_as_float(((unsigned int)xd[c]) & 0xffff0000u);        \
      acc[2 * c]     = fmaf((W), lo, acc[2 * c]);                             \
      acc[2 * c + 1] = fmaf((W), hi, acc[2 * c + 1]);                         \
    }                                                                         \
  }

    int i = 0;
    for (; i + 8 <= n; i += 8) {  // 8 votes: 4 uniform iv4 loads + 2 gathers
      iv4 r0 = __builtin_nontemporal_load((const iv4*)(s + 2 * i));
      iv4 r1 = __builtin_nontemporal_load((const iv4*)(s + 2 * i + 4));
      iv4 r2 = __builtin_nontemporal_load((const iv4*)(s + 2 * i + 8));
      iv4 r3 = __builtin_nontemporal_load((const iv4*)(s + 2 * i + 12));
      int im0; float w0; pick4(r0, r1, q, im0, w0);
      int im1; float w1; pick4(r2, r3, q, im1, w1);
      GATHER_FMA(im0, w0);
      GATHER_FMA(im1, w1);
    }
    for (; i < n; i += 4) {       // tail: one group of 4
      iv4 r0 = __builtin_nontemporal_load((const iv4*)(s + 2 * i));
      iv4 r1 = __builtin_nontemporal_load((const iv4*)(s + 2 * i + 4));
      int im0; float w0; pick4(r0, r1, q, im0, w0);
      GATHER_FMA(im0, w0);
    }
#undef GATHER_FMA

    // reduce across the 4 vote-quarters; lanes 0..15 hold channels cg*8..cg*8+7
#pragma unroll
    for (int k = 0; k < 8; ++k) {
      float t = acc[k] + __shfl_xor(acc[k], 16);
      acc[k] = t + __shfl_xor(t, 32);
    }
    if (lane < 16) {
      int row = (w * 4 + bi) * 129 + (cg << 3);
#pragma unroll
      for (int k = 0; k < 8; ++k) lacc[row + k] = acc[k];
    }
  }
  __syncthreads();

  // overflow fold-in (empty in practice: one scalar load, skip)
  int cnt = *ofl_cnt;
  if (cnt > 0) {
    if (cnt > OFL_CAP) cnt = OFL_CAP;
    if (tid < 128) {
      for (int v = 0; v < cnt; ++v) {
        int2 rec = ofl[v];
        int h = rec.x >> 14;
        if (h >= ht0 && h < ht0 + 32) {
          int imv = rec.x & 0x3FFF;
          float wv = __int_as_float(rec.y);
          float xv = __uint_as_float(((unsigned int)xTh[((size_t)imv << 7) + tid]) << 16);
          lacc[(h - ht0) * 129 + tid] += wv * xv;  // same thread per ch -> no race
        }
      }
    }
  }
  __syncthreads();

  // transposed write-out: out[ch][ht0 + j], 32 consecutive floats per row
#pragma unroll
  for (int k = 0; k < 8; ++k) {
    int ch = k * 16 + (tid >> 5);
    int j = tid & 31;
    out[(size_t)ch * NHT + ht0 + j] = lacc[j * 129 + ch];
  }
}

extern "C" void kernel_launch(void* const* d_in, const int* in_sizes, int n_in,
                              void* d_out, int out_size, void* d_ws, size_t ws_size,
                              hipStream_t stream) {
  const float* input_im = (const float*)d_in[0];
  const int*   im_idx   = (const int*)d_in[1];
  const int*   ht_idx   = (const int*)d_in[2];
  const float* weight   = (const float*)d_in[3];
  float*       out      = (float*)d_out;
  const int N = in_sizes[1];

  // workspace layout (~37.3 MB)
  char* w = (char*)d_ws;
  unsigned short* xTh = (unsigned short*)(w + 0);  //  4,194,304 B (HW*BC bf16)
  int2*  bkt     = (int2*) (w + 4194304);     // 16,392,192 B (NB*CAPB int2)
  int2*  fsorted = (int2*) (w + 20586496);    // 16,392,192 B
  int*   foffs   = (int*)  (w + 36978688);    //    132,480 B (NHT i32)
  int*   fcnt    = (int*)  (w + 37111168);    //    132,480 B
  int*   gcur    = (int*)  (w + 37243648);    //      2,304 B (NB, padded)
  int*   ofl_cnt = (int*)  (w + 37245952);    //        128 B
  int2*  ofl     = (int2*) (w + 37246080);    //     65,536 B

  k_init<<<2049, dim3(32, 8), 0, stream>>>(input_im, xTh, gcur, ofl_cnt);
  k_bucket<<<(N + VPB - 1) / VPB, 1024, 0, stream>>>(im_idx, ht_idx, weight, N,
                                                     gcur, bkt, ofl_cnt, ofl);
  k_resort<<<NB, 512, 0, stream>>>(bkt, gcur, fsorted, foffs, fcnt);
  k_accum6<<<NHT / 32, 512, 0, stream>>>(fsorted, foffs, fcnt, xTh, out,
                                         ofl_cnt, ofl);
}

// Round 11
// 138.265 us; speedup vs baseline: 1.1697x; 1.1697x over previous
//
#include <hip/hip_runtime.h>

// IM2HT Hough voting:
//   out[b,c,ht] = sum_{n: ht_idx[n]==ht} input_im[b,c,im_idx[n]] * weight[n]
// B*C = 128, HW = 16384, NHT = 184*180 = 33120, N = 1.5M votes.
//
// Pipeline (3 kernels):
//   1. k_init   : transpose in[BC][HW] -> xTh[HW][128] bf16 (4 MB = one XCD L2)
//                 + zero bucket cursors/overflow counter
//   2. k_bucket : multi-split votes into 552 coarse ht-ranges (60 bins each);
//                 1024 thr x 4 votes; per-block private chunks -> merged writes
//   3. k_accum8 : one 1024-thr block per range (16 waves = 34 waves/CU):
//                 LDS-stage records -> in-LDS counting sort by fine bin (padded
//                 to x4) -> waves 0..14 accumulate 4 bins each via quarter-wave
//                 bf16x8 gathers (1 gather instr per 4 votes, L2-resident),
//                 records read as broadcast ds_reads -> lacc[60][129] (overlaid
//                 on staging buf) -> fused transposed write out[ch][r*60+j]
//                 (+ overflow fold-in, empty in practice)

#define HW   16384
#define BC   128
#define NHT  33120
#define RB   60            // ht bins per coarse range
#define NB   552           // NHT / RB
#define CAPB 3712          // bkt slots per range (mean 2717)
#define CAPR 3528          // raw record clamp, +15 sigma
#define CAPD 3712          // sorted slots (<= 3528 + 3*60 = 3708)
#define VPB  4096          // votes per k_bucket block
#define OFL_CAP 8192

typedef int iv4 __attribute__((ext_vector_type(4)));

__device__ __forceinline__ unsigned short f2bf(float f) {
  unsigned int u = __float_as_uint(f);
  u = (u + 0x7fff + ((u >> 16) & 1)) >> 16;   // round-to-nearest-even
  return (unsigned short)u;
}

// blocks 0..2047: transpose in[BC][HW] f32 -> xTh[HW][BC] bf16; block 2048: zero
__global__ void k_init(const float* __restrict__ in, unsigned short* __restrict__ xTh,
                       int* __restrict__ gcur, int* __restrict__ ofl_cnt) {
  if (blockIdx.x == 2048) {
    int tid = threadIdx.y * 32 + threadIdx.x;
    for (int i = tid; i < NB; i += 256) gcur[i] = 0;
    if (tid == 0) *ofl_cnt = 0;
    return;
  }
  __shared__ float tile[32][33];
  int hw0 = (blockIdx.x & 511) * 32, bc0 = (blockIdx.x >> 9) * 32;
  int tx = threadIdx.x, ty = threadIdx.y;
#pragma unroll
  for (int k = 0; k < 32; k += 8)
    tile[ty + k][tx] = in[(size_t)(bc0 + ty + k) * HW + hw0 + tx];  // coalesced on hw
  __syncthreads();
#pragma unroll
  for (int k = 0; k < 32; k += 8)
    xTh[(size_t)(hw0 + ty + k) * BC + bc0 + tx] = f2bf(tile[tx][ty + k]);
}

// 1024 threads, 4 votes each (VPB = 4096 -> private-chunk write combining)
__global__ __launch_bounds__(1024) void k_bucket(
    const int* __restrict__ im, const int* __restrict__ ht,
    const float* __restrict__ wt, int n,
    int* __restrict__ gcur, int2* __restrict__ bkt,
    int* __restrict__ ofl_cnt, int2* __restrict__ ofl) {
  __shared__ int cnt[NB];
  __shared__ int base[NB];
  int tid = threadIdx.x;
  int i0 = blockIdx.x * VPB;
  for (int b = tid; b < NB; b += 1024) cnt[b] = 0;
  __syncthreads();
  int hv[4];
#pragma unroll
  for (int k = 0; k < 4; ++k) {
    int i = i0 + k * 1024 + tid;
    hv[k] = (i < n) ? ht[i] : -1;
    if (i < n) atomicAdd(&cnt[hv[k] / RB], 1);
  }
  __syncthreads();
  for (int b = tid; b < NB; b += 1024) {
    int c = cnt[b];
    base[b] = c ? atomicAdd(&gcur[b], c) : 0;  // reserve private chunk
    cnt[b] = 0;                                 // reuse as local cursor
  }
  __syncthreads();
#pragma unroll
  for (int k = 0; k < 4; ++k) {
    int i = i0 + k * 1024 + tid;
    if (i < n) {
      int h = hv[k];
      int b = h / RB;
      int hl = h - b * RB;
      int pos = base[b] + atomicAdd(&cnt[b], 1);
      if (pos < CAPR) {
        bkt[(size_t)b * CAPB + pos] =
            make_int2((im[i] & 0x3FFF) | (hl << 14), __float_as_int(wt[i]));
      } else {
        int o = atomicAdd(ofl_cnt, 1);
        if (o < OFL_CAP)
          ofl[o] = make_int2((im[i] & 0x3FFF) | (h << 14), __float_as_int(wt[i]));
      }
    }
  }
}

// select vote from broadcast LDS record; quarter-wave gather accumulate
__global__ __launch_bounds__(1024) void k_accum8(
    const int2* __restrict__ bkt, const int* __restrict__ gcur,
    const unsigned short* __restrict__ xTh, float* __restrict__ out,
    const int* __restrict__ ofl_cnt, const int2* __restrict__ ofl) {
  __shared__ int2 sdst[CAPD];                  // 29,696 B sorted records
  __shared__ float lacc[RB * 129];             // 30,960 B; staging buf overlaid
  __shared__ int hist[RB], off[RB], pcnt[RB], cur[RB];
  int2* buf = (int2*)lacc;                     // dead before lacc writes begin
  int tid = threadIdx.x;
  int r = blockIdx.x;
  int ht0 = r * RB;
  int n = gcur[r];
  if (n > CAPR) n = CAPR;
  const int2* s = bkt + (size_t)r * CAPB;
  for (int i = tid; i < n; i += 1024) buf[i] = s[i];   // single global read
  if (tid < RB) hist[tid] = 0;
  __syncthreads();
  for (int i = tid; i < n; i += 1024)
    atomicAdd(&hist[buf[i].x >> 14], 1);
  __syncthreads();
  if (tid < 64) {                              // wave-0 shfl inclusive scan
    int v = (tid < RB) ? ((hist[tid] + 3) & ~3) : 0;
    int inc = v;
#pragma unroll
    for (int d = 1; d < 64; d <<= 1) {
      int t = __shfl_up(inc, d);
      if (tid >= d) inc += t;
    }
    if (tid < RB) { off[tid] = inc - v; pcnt[tid] = v; cur[tid] = 0; }
  }
  __syncthreads();
  if (tid < RB) {                              // weight-0 dummies in pad slots
    for (int d = hist[tid]; d < pcnt[tid]; ++d)
      sdst[off[tid] + d] = make_int2(0, 0);
  }
  for (int i = tid; i < n; i += 1024) {        // scatter into sorted order
    int2 v = buf[i];
    int hl = v.x >> 14;
    int pos = off[hl] + atomicAdd(&cur[hl], 1);
    sdst[pos] = make_int2(v.x & 0x3FFF, v.y);
  }
  __syncthreads();

  // accumulate: wave w (0..14) handles bins w*4 .. w*4+3; lane=(quarter q, octet cg)
  int w = __builtin_amdgcn_readfirstlane(tid >> 6);
  int lane = tid & 63;
  int q = lane >> 4;
  int cg = lane & 15;
  const unsigned short* xb = xTh + (cg << 3);
  if (w < 15) {
#pragma unroll
    for (int bi = 0; bi < 4; ++bi) {
      int bin = w * 4 + bi;
      int o = off[bin], nb = pcnt[bin];        // nb % 4 == 0
      float acc[8] = {0, 0, 0, 0, 0, 0, 0, 0};

#define GATHER_FMA(IM, W)                                                     \
  {                                                                           \
    iv4 xd = *(const iv4*)(xb + ((size_t)(IM) << 7));                         \
    _Pragma("unroll") for (int c = 0; c < 4; ++c) {                           \
      float lo = __uint_as_float(((unsigned int)xd[c]) << 16);                \
      float hi = __uint_as_float(((unsigned int)xd[c]) & 0xffff0000u);        \
      acc[2 * c]     = fmaf((W), lo, acc[2 * c]);                             \
      acc[2 * c + 1] = fmaf((W), hi, acc[2 * c + 1]);                         \
    }                                                                         \
  }

      int i = 0;
      for (; i + 8 <= nb; i += 8) {            // 8 votes: 2 broadcast ds_reads + 2 gathers
        int2 r0 = sdst[o + i + q];
        int2 r1 = sdst[o + i + 4 + q];
        GATHER_FMA(r0.x, __int_as_float(r0.y));
        GATHER_FMA(r1.x, __int_as_float(r1.y));
      }
      for (; i < nb; i += 4) {
        int2 r0 = sdst[o + i + q];
        GATHER_FMA(r0.x, __int_as_float(r0.y));
      }
#undef GATHER_FMA

      // reduce across the 4 vote-quarters
#pragma unroll
      for (int k = 0; k < 8; ++k) {
        float t = acc[k] + __shfl_xor(acc[k], 16);
        acc[k] = t + __shfl_xor(t, 32);
      }
      if (lane < 16) {
        int row = bin * 129 + (cg << 3);
#pragma unroll
        for (int k = 0; k < 8; ++k) lacc[row + k] = acc[k];
      }
    }
  }
  __syncthreads();

  // overflow fold-in (empty in practice: one scalar load, skip)
  int cnt = *ofl_cnt;
  if (cnt > 0) {
    if (cnt > OFL_CAP) cnt = OFL_CAP;
    if (tid < 128) {
      for (int v = 0; v < cnt; ++v) {
        int2 rec = ofl[v];
        int h = rec.x >> 14;
        if (h >= ht0 && h < ht0 + RB) {
          int imv = rec.x & 0x3FFF;
          float wv = __int_as_float(rec.y);
          float xv = __uint_as_float(((unsigned int)xTh[((size_t)imv << 7) + tid]) << 16);
          lacc[(h - ht0) * 129 + tid] += wv * xv;  // same thread per ch -> no race
        }
      }
    }
    __syncthreads();
  }

  // transposed write-out: out[ch][ht0 + jj]; 8 lanes per ch -> 32 B runs
  int ch = tid >> 3;
  for (int jj = tid & 7; jj < RB; jj += 8)
    out[(size_t)ch * NHT + ht0 + jj] = lacc[jj * 129 + ch];
}

extern "C" void kernel_launch(void* const* d_in, const int* in_sizes, int n_in,
                              void* d_out, int out_size, void* d_ws, size_t ws_size,
                              hipStream_t stream) {
  const float* input_im = (const float*)d_in[0];
  const int*   im_idx   = (const int*)d_in[1];
  const int*   ht_idx   = (const int*)d_in[2];
  const float* weight   = (const float*)d_in[3];
  float*       out      = (float*)d_out;
  const int N = in_sizes[1];

  // workspace layout (~20.7 MB)
  char* w = (char*)d_ws;
  unsigned short* xTh = (unsigned short*)(w + 0);  //  4,194,304 B (HW*BC bf16)
  int2*  bkt     = (int2*) (w + 4194304);     // 16,392,192 B (NB*CAPB int2)
  int*   gcur    = (int*)  (w + 20586496);    //      2,304 B (NB, padded)
  int*   ofl_cnt = (int*)  (w + 20588800);    //        128 B
  int2*  ofl     = (int2*) (w + 20588928);    //     65,536 B

  k_init<<<2049, dim3(32, 8), 0, stream>>>(input_im, xTh, gcur, ofl_cnt);
  k_bucket<<<(N + VPB - 1) / VPB, 1024, 0, stream>>>(im_idx, ht_idx, weight, N,
                                                     gcur, bkt, ofl_cnt, ofl);
  k_accum8<<<NB, 1024, 0, stream>>>(bkt, gcur, xTh, out, ofl_cnt, ofl);
}